// Round 12
// baseline (89.643 us; speedup 1.0000x reference)
//
#include <hip/hip_runtime.h>
#include <hip/hip_bf16.h>
#include <math.h>

#define HID 128
#define ATT 64
#define HOPS 8
#define T_ 64
#define N_ 64
#define B_ 64
#define L_ 4096

typedef __attribute__((ext_vector_type(8))) short bf16x8;
typedef __attribute__((ext_vector_type(4))) float f32x4;

static constexpr size_t OFF_A     = (size_t)B_ * N_ * T_;              // 262144
static constexpr size_t OFF_NEIGH = OFF_A + (size_t)B_ * HOPS * L_;    // 2359296
static constexpr size_t OFF_PENAL = OFF_NEIGH + (size_t)B_ * L_ * HID; // 35913728

__device__ __forceinline__ unsigned pkbf(float lo, float hi) {
    unsigned a = (unsigned)(unsigned short)__builtin_bit_cast(unsigned short, __float2bfloat16(lo));
    unsigned b = (unsigned)(unsigned short)__builtin_bit_cast(unsigned short, __float2bfloat16(hi));
    return a | (b << 16);
}
__device__ __forceinline__ short f2bf(float x) {
    return __builtin_bit_cast(short, __float2bfloat16(x));
}

typedef const __attribute__((address_space(1))) unsigned g1u32;
typedef __attribute__((address_space(3))) unsigned l3u32;

// DMA one 16-row strip (8 KB) into wave-private LDS: 8 x global_load_lds width 16.
// LDS dest is wave-uniform base (+lane*16 by HW); global source is per-lane.
__device__ __forceinline__ void stage_strip(const float* src, unsigned* lds, int lane) {
    #pragma unroll
    for (int t = 0; t < 8; ++t) {
        __builtin_amdgcn_global_load_lds((g1u32*)((const unsigned*)src + t * 256 + lane * 4),
                                         (l3u32*)(lds + t * 256), 16, 0, 0);
    }
}

template<int WN> __device__ __forceinline__ void vwait() {
    if constexpr (WN == 8)       asm volatile("s_waitcnt vmcnt(8)" ::: "memory");
    else if constexpr (WN == 17) asm volatile("s_waitcnt vmcnt(17)" ::: "memory");
    else                         asm volatile("s_waitcnt vmcnt(9)" ::: "memory");
}

// Per-strip compute: af from LDS f32 x node-regs -> bf16, 16 MFMA s1 (W1 in regs),
// copy-out via LDS->reg->global (full 512B-contiguous spans), tanh -> th aliased
// into the (dead-after-reads) current buffer, 2 MFMA s2, store. 9 global stores.
__device__ __forceinline__ void compute_strip(
    unsigned* hb, float* cd, float* s2p,
    const float nf[4][8], const bf16x8 wf[4][4], const bf16x8 wf2[2],
    const float b1v[4], float b2v, float inv_scale,
    int c, int g, int ro, int p)
{
    // ---- A-fragments: ds_read f32 row c, multiply by node, pack bf16 ----
    bf16x8 af[4];
    #pragma unroll
    for (int ks = 0; ks < 4; ++ks) {
        const float* hr = (const float*)hb + c * 128 + ks * 32 + g * 8;
        float4 a = *(const float4*)hr;
        float4 b = *(const float4*)(hr + 4);
        union { bf16x8 v; unsigned u[4]; } t;
        t.u[0] = pkbf(a.x * nf[ks][0], a.y * nf[ks][1]);
        t.u[1] = pkbf(a.z * nf[ks][2], a.w * nf[ks][3]);
        t.u[2] = pkbf(b.x * nf[ks][4], b.y * nf[ks][5]);
        t.u[3] = pkbf(b.z * nf[ks][6], b.w * nf[ks][7]);
        af[ks] = t.v;
    }
    // ---- copy-out: LDS -> regs -> global (2 rows x 512B contiguous per instr) ----
    float4 cr[8];
    #pragma unroll
    for (int j = 0; j < 8; ++j)
        cr[j] = *(const float4*)((const float*)hb + (2 * j + ro) * 128 + p * 4);
    #pragma unroll
    for (int j = 0; j < 8; ++j)
        *(float4*)(cd + (2 * j + ro) * 128 + p * 4) = cr[j];

    // ---- s1 GEMM: 16 MFMA, W1 fragments in VGPRs ----
    f32x4 acc[4];
    #pragma unroll
    for (int cf = 0; cf < 4; ++cf) acc[cf] = (f32x4){0.f, 0.f, 0.f, 0.f};
    #pragma unroll
    for (int cf = 0; cf < 4; ++cf) {
        #pragma unroll
        for (int ks = 0; ks < 4; ++ks)
            acc[cf] = __builtin_amdgcn_mfma_f32_16x16x32_bf16(af[ks], wf[cf][ks], acc[cf], 0, 0, 0);
    }

    // compile-time fence: th writes below alias hb; keep them after the reads above
    asm volatile("" ::: "memory");

    // ---- tanh -> th tile aliased into current buffer (dead after reads) ----
    short* thw = (short*)hb;
    #pragma unroll
    for (int cf = 0; cf < 4; ++cf) {
        #pragma unroll
        for (int jj = 0; jj < 4; ++jj) {
            float th = (acc[cf][jj] + b1v[cf]) * inv_scale;
            th = 1.0f - 2.0f / (__expf(2.0f * th) + 1.0f);   // tanh, inf-safe
            thw[(g * 4 + jj) * 72 + cf * 16 + c] = f2bf(th);
        }
    }
    // ---- s2 MFMA + store ----
    f32x4 acc2 = (f32x4){0.f, 0.f, 0.f, 0.f};
    #pragma unroll
    for (int ks2 = 0; ks2 < 2; ++ks2) {
        bf16x8 pa = *reinterpret_cast<const bf16x8*>(&thw[c * 72 + ks2 * 32 + g * 8]);
        acc2 = __builtin_amdgcn_mfma_f32_16x16x32_bf16(pa, wf2[ks2], acc2, 0, 0, 0);
    }
    if (c < 8) {
        float4 o;
        o.x = acc2[0] + b2v; o.y = acc2[1] + b2v;
        o.z = acc2[2] + b2v; o.w = acc2[3] + b2v;
        *(float4*)&s2p[(size_t)c * L_ + g * 4] = o;
    }
}

// ---------------- K1: wave-independent DMA-staged strips, zero barriers ----------------
// 512 blocks x 256 thr = 2048 waves, all resident (2 blocks/CU, 64 KB LDS).
// Wave Wv: batch Wv>>5, strips (Wv&31) + 32k, k=0..7; dbuf in wave-private LDS.
// Counted vmcnt per iter: stage(k+1)=8 gload_lds, stores/iter = 8 copy + 1 s2 = 9.
//   k=0: newer-than-stage(0) = stage(1) -> vmcnt(8)
//   k=1..6: newer = stores(k-1)[9] + stage(k+1)[8] -> vmcnt(17)
//   k=7: newer = stores(6)[9] -> vmcnt(9)
__global__ __launch_bounds__(256, 2)
void k1_mfma(const float* __restrict__ node, const float* __restrict__ neigh,
             const int* __restrict__ nnum, const float* __restrict__ W1,
             const float* __restrict__ b1, const float* __restrict__ W2,
             const float* __restrict__ b2, float* __restrict__ out)
{
    __shared__ __align__(16) unsigned sbuf[2][4][2048];    // 64 KB: [buf][wave][8KB]

    const int tid  = threadIdx.x;
    const int w    = tid >> 6;
    const int lane = tid & 63;
    const int c    = lane & 15;
    const int g    = lane >> 4;
    const int ro   = lane >> 5;
    const int p    = lane & 31;

    const int Wv    = blockIdx.x * 4 + w;     // 0..2047
    const int batch = Wv >> 5;
    const int widx  = Wv & 31;

    const float* nb0 = neigh + (size_t)batch * 524288 + (size_t)widx * 2048;
    float*       cd0 = out + OFF_NEIGH + (size_t)batch * 524288 + (size_t)widx * 2048;
    float*       s2b = out + OFF_A + (size_t)batch * 32768 + (size_t)widx * 16;

    unsigned* buf0 = &sbuf[0][w][0];
    unsigned* buf1 = &sbuf[1][w][0];

    stage_strip(nb0, buf0, lane);              // strip 0 DMA in flight

    // ---- node fragment rows (loop-invariant: row = (widx&3)*16 + c), f32 ----
    float nf[4][8];
    {
        const float* nd = node + (size_t)batch * 8192 + ((widx & 3) * 16 + c) * 128;
        #pragma unroll
        for (int ks = 0; ks < 4; ++ks) {
            float4 a = *(const float4*)(nd + ks * 32 + g * 8);
            float4 b = *(const float4*)(nd + ks * 32 + g * 8 + 4);
            nf[ks][0] = a.x; nf[ks][1] = a.y; nf[ks][2] = a.z; nf[ks][3] = a.w;
            nf[ks][4] = b.x; nf[ks][5] = b.y; nf[ks][6] = b.z; nf[ks][7] = b.w;
        }
    }
    // ---- W1 B-fragments in VGPRs ----
    bf16x8 wf[4][4];
    #pragma unroll
    for (int cf = 0; cf < 4; ++cf) {
        const float* wr = W1 + (cf * 16 + c) * 128;
        #pragma unroll
        for (int ks = 0; ks < 4; ++ks) {
            float4 a = *(const float4*)(wr + ks * 32 + g * 8);
            float4 b = *(const float4*)(wr + ks * 32 + g * 8 + 4);
            union { bf16x8 v; unsigned u[4]; } t;
            t.u[0] = pkbf(a.x, a.y); t.u[1] = pkbf(a.z, a.w);
            t.u[2] = pkbf(b.x, b.y); t.u[3] = pkbf(b.z, b.w);
            wf[cf][ks] = t.v;
        }
    }
    // ---- W2 B-fragments, biases ----
    bf16x8 wf2[2];
    #pragma unroll
    for (int ks2 = 0; ks2 < 2; ++ks2) {
        union { bf16x8 v; unsigned u[4]; } t;
        #pragma unroll
        for (int i = 0; i < 4; ++i) {
            float lo = (c < 8) ? W2[c * 64 + ks2 * 32 + g * 8 + 2 * i]     : 0.f;
            float hi = (c < 8) ? W2[c * 64 + ks2 * 32 + g * 8 + 2 * i + 1] : 0.f;
            t.u[i] = pkbf(lo, hi);
        }
        wf2[ks2] = t.v;
    }
    float b1v[4];
    #pragma unroll
    for (int cf = 0; cf < 4; ++cf) b1v[cf] = b1[cf * 16 + c];
    const float b2v = (c < 8) ? b2[c] : 0.f;
    const float inv_scale = rsqrtf((float)nnum[0]);

    // ---- 8 strips, fully unrolled, dbuf parity: strip k in buf[k&1] ----
    stage_strip(nb0 + 1 * 65536, buf1, lane);
    vwait<8>();
    compute_strip(buf0, cd0, s2b, nf, wf, wf2, b1v, b2v, inv_scale, c, g, ro, p);

    stage_strip(nb0 + 2 * 65536, buf0, lane);
    vwait<17>();
    compute_strip(buf1, cd0 + 1 * 65536, s2b + 512, nf, wf, wf2, b1v, b2v, inv_scale, c, g, ro, p);

    stage_strip(nb0 + 3 * 65536, buf1, lane);
    vwait<17>();
    compute_strip(buf0, cd0 + 2 * 65536, s2b + 1024, nf, wf, wf2, b1v, b2v, inv_scale, c, g, ro, p);

    stage_strip(nb0 + 4 * 65536, buf0, lane);
    vwait<17>();
    compute_strip(buf1, cd0 + 3 * 65536, s2b + 1536, nf, wf, wf2, b1v, b2v, inv_scale, c, g, ro, p);

    stage_strip(nb0 + 5 * 65536, buf1, lane);
    vwait<17>();
    compute_strip(buf0, cd0 + 4 * 65536, s2b + 2048, nf, wf, wf2, b1v, b2v, inv_scale, c, g, ro, p);

    stage_strip(nb0 + 6 * 65536, buf0, lane);
    vwait<17>();
    compute_strip(buf1, cd0 + 5 * 65536, s2b + 2560, nf, wf, wf2, b1v, b2v, inv_scale, c, g, ro, p);

    stage_strip(nb0 + 7 * 65536, buf1, lane);
    vwait<17>();
    compute_strip(buf0, cd0 + 6 * 65536, s2b + 3072, nf, wf, wf2, b1v, b2v, inv_scale, c, g, ro, p);

    vwait<9>();
    compute_strip(buf1, cd0 + 7 * 65536, s2b + 3584, nf, wf, wf2, b1v, b2v, inv_scale, c, g, ro, p);
}

// ---------------- reductions helpers ----------------
__device__ __forceinline__ float waveMax(float v) {
    #pragma unroll
    for (int o = 32; o > 0; o >>= 1) v = fmaxf(v, __shfl_xor(v, o));
    return v;
}
__device__ __forceinline__ float waveSum(float v) {
    #pragma unroll
    for (int o = 32; o > 0; o >>= 1) v += __shfl_xor(v, o);
    return v;
}

// ---------------- K2: per-(b,h) softmax stats + zero aat accumulators ----------------
__global__ __launch_bounds__(256)
void k2_stats(const float* __restrict__ out, float* __restrict__ stats, float* __restrict__ aat)
{
    const int bh = blockIdx.x;                         // 0..511
    const int tid = threadIdx.x;
    if (bh == 0) {
        for (int i = tid; i < B_ * 36; i += 256) aat[i] = 0.f;
    }
    const float* row = out + OFF_A + (size_t)bh * L_;
    __shared__ float red[8];
    float m = -3.4e38f;
    for (int i = tid; i < L_; i += 256) m = fmaxf(m, row[i]);
    m = waveMax(m);
    if ((tid & 63) == 0) red[tid >> 6] = m;
    __syncthreads();
    const float M = fmaxf(fmaxf(red[0], red[1]), fmaxf(red[2], red[3]));
    float s = 0.0f;
    for (int i = tid; i < L_; i += 256) s += __expf(row[i] - M);
    s = waveSum(s);
    if ((tid & 63) == 0) red[4 + (tid >> 6)] = s;
    __syncthreads();
    if (tid == 0) {
        stats[bh * 2]     = M;
        stats[bh * 2 + 1] = red[4] + red[5] + red[6] + red[7];
    }
}

// ---------------- K3: in-place A = softmax, BW, AAT upper-tri partials (atomic) -------
__global__ __launch_bounds__(256)
void k3_soft(float* __restrict__ out, const float* __restrict__ stats, float* __restrict__ aat)
{
    const int blk = blockIdx.x;        // 256 blocks, 4 per batch
    const int b   = blk >> 2;
    const int l0  = (blk & 3) << 10;   // 1024 l's each
    const int tid = threadIdx.x;
    float* A0 = out + OFF_A + (size_t)b * HOPS * L_;
    float* BW = out + (size_t)b * L_;
    float M[HOPS], R[HOPS];
    #pragma unroll
    for (int hh = 0; hh < HOPS; ++hh) {
        M[hh] = stats[(b * HOPS + hh) * 2];
        R[hh] = 1.0f / stats[(b * HOPS + hh) * 2 + 1];
    }
    float p[36];
    #pragma unroll
    for (int i = 0; i < 36; ++i) p[i] = 0.0f;
    for (int l = l0 + tid; l < l0 + 1024; l += 256) {
        float e[HOPS]; float srow = 0.0f;
        #pragma unroll
        for (int hh = 0; hh < HOPS; ++hh) {
            float v = __expf(A0[hh * L_ + l] - M[hh]) * R[hh];
            e[hh] = v; srow += v;
        }
        #pragma unroll
        for (int hh = 0; hh < HOPS; ++hh) A0[hh * L_ + l] = e[hh];
        BW[l] = srow;
        int i = 0;
        #pragma unroll
        for (int hh = 0; hh < HOPS; ++hh) {
            #pragma unroll
            for (int gg = hh; gg < HOPS; ++gg) { p[i] = fmaf(e[hh], e[gg], p[i]); ++i; }
        }
    }
    #pragma unroll
    for (int i = 0; i < 36; ++i) p[i] = waveSum(p[i]);
    __shared__ float red[4][36];
    const int wv = tid >> 6, ln = tid & 63;
    if (ln == 0) {
        #pragma unroll
        for (int i = 0; i < 36; ++i) red[wv][i] = p[i];
    }
    __syncthreads();
    if (tid < 36) {
        float s = red[0][tid] + red[1][tid] + red[2][tid] + red[3][tid];
        atomicAdd(&aat[b * 36 + tid], s);
    }
}

// ---------------- K4: penal = sum_b sum((AAT_b - I)^2), off-diag counted twice --------
__global__ __launch_bounds__(256)
void k4_penal(const float* __restrict__ aat, float* __restrict__ out)
{
    const int tid = threadIdx.x;
    float s = 0.0f;
    for (int i = tid; i < B_ * 36; i += 256) {
        int r = i % 36;
        bool dg = (r == 0) | (r == 8) | (r == 15) | (r == 21) |
                  (r == 26) | (r == 30) | (r == 33) | (r == 35);
        float d = aat[i] - (dg ? 1.0f : 0.0f);
        float qd = d * d;
        s += dg ? qd : 2.0f * qd;
    }
    s = waveSum(s);
    __shared__ float red[4];
    if ((tid & 63) == 0) red[tid >> 6] = s;
    __syncthreads();
    if (tid == 0) out[OFF_PENAL] = red[0] + red[1] + red[2] + red[3];
}

extern "C" void kernel_launch(void* const* d_in, const int* in_sizes, int n_in,
                              void* d_out, int out_size, void* d_ws, size_t ws_size,
                              hipStream_t stream) {
    const float* node  = (const float*)d_in[0];
    const float* neigh = (const float*)d_in[1];
    const int*   nnum  = (const int*)d_in[2];   // low 32 bits of elem 0 (LE, value in [1,64))
    const float* W1    = (const float*)d_in[3];
    const float* b1    = (const float*)d_in[4];
    const float* W2    = (const float*)d_in[5];
    const float* b2    = (const float*)d_in[6];
    float* out   = (float*)d_out;
    float* stats = (float*)d_ws;          // 1024 floats
    float* aat   = stats + 1024;          // 64*36 floats (upper-tri, accumulated)

    k1_mfma <<<512, 256, 0, stream>>>(node, neigh, nnum, W1, b1, W2, b2, out);
    k2_stats<<<B_ * HOPS, 256, 0, stream>>>(out, stats, aat);
    k3_soft <<<256, 256, 0, stream>>>(out, stats, aat);
    k4_penal<<<1, 256, 0, stream>>>(aat, out);
}